// Round 10
// baseline (214.613 us; speedup 1.0000x reference)
//
#include <hip/hip_runtime.h>

typedef __bf16 bf16x8 __attribute__((ext_vector_type(8)));
typedef float f32x4 __attribute__((ext_vector_type(4)));
typedef int i32x8 __attribute__((ext_vector_type(8)));

// ---------------------------------------------------------------------------
// Problem constants: B=2, C=512, H=W=64 -> N=4096, 32 groups (16 ch/group)
// ---------------------------------------------------------------------------

#if defined(__has_builtin)
#if __has_builtin(__builtin_amdgcn_global_load_lds)
#define HAS_GLL 1
#endif
#endif

__device__ __forceinline__ void async_copy16(const void* g, void* l) {
#ifdef HAS_GLL
    __builtin_amdgcn_global_load_lds(
        (const __attribute__((address_space(1))) unsigned int*)g,
        (__attribute__((address_space(3))) unsigned int*)l, 16, 0, 0);
#else
    *(int4*)l = *(const int4*)g;
#endif
}

__device__ __forceinline__ unsigned char to_fp8(float v) {
    return (unsigned char)(__builtin_amdgcn_cvt_pk_fp8_f32(v, v, 0, false) & 0xFF);
}

#define MXSCALE 0x7F7F7F7F  // e8m0 1.0 in every byte

// --- Merged: GroupNorm channel partial sums (blocks 0..1023) +
//             weight cast fp32->fp8/bf16 (blocks 1024..2047) ----------------
__global__ __launch_bounds__(256) void prep_kernel(
    const float* __restrict__ x, float* __restrict__ ps,
    const float* __restrict__ wq, const float* __restrict__ wk,
    const float* __restrict__ wv, const float* __restrict__ wp,
    const float* __restrict__ bq, const float* __restrict__ bk,
    unsigned char* __restrict__ wqk8, unsigned char* __restrict__ wv8,
    __bf16* __restrict__ wp_b, float* __restrict__ bqk) {
    if (blockIdx.x >= 1024) {
        int idx = (blockIdx.x - 1024) * 256 + threadIdx.x;  // 262144 = 512*512
        wqk8[idx] = to_fp8(wq[idx]);
        wqk8[262144 + idx] = to_fp8(wk[idx]);
        wv8[idx] = to_fp8(wv[idx]);
        wp_b[idx] = (__bf16)wp[idx];
        if (idx < 512) {
            bqk[idx] = bq[idx];
            bqk[512 + idx] = bk[idx];
        }
        return;
    }
    int blk = blockIdx.x;  // one (b,c) channel: 4096 floats
    const float4* base = (const float4*)x + (size_t)blk * 1024;
    float s1 = 0.f, s2 = 0.f;
#pragma unroll
    for (int i = 0; i < 4; ++i) {
        float4 v = base[threadIdx.x + (i << 8)];
        s1 += v.x + v.y + v.z + v.w;
        s2 += v.x * v.x + v.y * v.y + v.z * v.z + v.w * v.w;
    }
    for (int off = 32; off >= 1; off >>= 1) {
        s1 += __shfl_xor(s1, off);
        s2 += __shfl_xor(s2, off);
    }
    __shared__ float r1[4], r2[4];
    int wave = threadIdx.x >> 6, lane = threadIdx.x & 63;
    if (lane == 0) { r1[wave] = s1; r2[wave] = s2; }
    __syncthreads();
    if (threadIdx.x == 0) {
        ps[blk] = r1[0] + r1[1] + r1[2] + r1[3];
        ps[1024 + blk] = r2[0] + r2[1] + r2[2] + r2[3];
    }
}

// -- GroupNorm finalize + apply + transpose: x[b][c][n] -> hn8[b][n][c] fp8 --
__global__ __launch_bounds__(256) void gn_apply_kernel(const float* __restrict__ x,
                                                       const float* __restrict__ gn_scale,
                                                       const float* __restrict__ gn_bias,
                                                       const float* __restrict__ ps,
                                                       unsigned char* __restrict__ hn8) {
    __shared__ float tile[32][33];
    int b = blockIdx.z;
    int n0 = blockIdx.x * 32, c0 = blockIdx.y * 32;
    int tx = threadIdx.x & 31, ty = threadIdx.x >> 5;  // ty in 0..7
    const float* xb = x + (size_t)b * 512 * 4096;
#pragma unroll
    for (int r = 0; r < 4; ++r) {
        int c = ty + r * 8;
        tile[c][tx] = xb[(size_t)(c0 + c) * 4096 + n0 + tx];
    }
    int c = c0 + tx;
    int g = (b << 5) + (c >> 4);
    float s1 = 0.f, s2 = 0.f;
#pragma unroll
    for (int i = 0; i < 16; ++i) {
        s1 += ps[(g << 4) + i];
        s2 += ps[1024 + (g << 4) + i];
    }
    float m = s1 * (1.f / 65536.f);
    float var = s2 * (1.f / 65536.f) - m * m;
    float rs = rsqrtf(var + 1e-6f);
    float sc = gn_scale[c] * rs;
    float bi = gn_bias[c] - m * sc;
    __syncthreads();
    unsigned char* outp = hn8 + (size_t)b * 4096 * 512;
#pragma unroll
    for (int r = 0; r < 4; ++r) {
        int n = ty + r * 8;
        float v = tile[tx][n];
        outp[(size_t)(n0 + n) * 512 + c] = to_fp8(v * sc + bi);
    }
}

// ---------------------------------------------------------------------------
// Shared MX fp8 GEMM body (m148 structure): C = s * A[m][k] * Bt[n][k] (+bias).
// mfma_scale_f32_16x16x128_f8f6f4 (scales=1.0), BM=128, BK=128.
// A/B frag: row = lane&15, k = (lane>>4)*32 + j.  C/D: col=lane&15,
// row=(lane>>4)*4+r. [r7/r8-verified]  OUT: 0=fp8, 1=fp16. BIAS: 0/1=row/2=col.
// ---------------------------------------------------------------------------
template <int BN, int OUT_MODE, int BIAS_MODE>
__device__ __forceinline__ void mx_gemm_body(
    const unsigned char* __restrict__ Ab, int lda,
    const unsigned char* __restrict__ Bb, int ldb,
    void* __restrict__ C, int ldc,
    const float* __restrict__ bias, int K, float scale,
    long m0, long n0, unsigned char* As, unsigned char* Bs) {
    constexpr int NT = BN / 32;  // 4 or 2
    const int tid = threadIdx.x;
    const int lane = tid & 63, wave = tid >> 6;
    const int ln = lane & 15, q = lane >> 4;
    const int wm = (wave >> 1) << 6;
    const int wn = (wave & 1) * (BN / 2);

    f32x4 acc[4][NT] = {};

    for (int k0 = 0; k0 < K; k0 += 128) {
        __syncthreads();
#pragma unroll
        for (int p = 0; p < 4; ++p) {
            int c = (p << 8) + tid;  // A: 1024 chunks of 16B
            int row = c >> 3, sg = (c & 7) << 4;
            async_copy16(Ab + (long)row * lda + k0 + sg, &As[c << 4]);
        }
#pragma unroll
        for (int p = 0; p < BN / 32; ++p) {
            int c = (p << 8) + tid;
            int row = c >> 3, sg = (c & 7) << 4;
            async_copy16(Bb + (long)row * ldb + k0 + sg, &Bs[c << 4]);
        }
        __syncthreads();
        i32x8 af[4], bf[NT];
#pragma unroll
        for (int t = 0; t < 4; ++t) {
            const unsigned char* ap = &As[(wm + t * 16 + ln) * 128 + (q << 5)];
            *(int4*)&af[t] = *(const int4*)ap;
            *((int4*)&af[t] + 1) = *(const int4*)(ap + 16);
        }
#pragma unroll
        for (int t = 0; t < NT; ++t) {
            const unsigned char* bp = &Bs[(wn + t * 16 + ln) * 128 + (q << 5)];
            *(int4*)&bf[t] = *(const int4*)bp;
            *((int4*)&bf[t] + 1) = *(const int4*)(bp + 16);
        }
#pragma unroll
        for (int mt = 0; mt < 4; ++mt)
#pragma unroll
            for (int nt = 0; nt < NT; ++nt)
                acc[mt][nt] = __builtin_amdgcn_mfma_scale_f32_16x16x128_f8f6f4(
                    af[mt], bf[nt], acc[mt][nt], 0, 0, 0, MXSCALE, 0, MXSCALE);
    }

#pragma unroll
    for (int mt = 0; mt < 4; ++mt) {
#pragma unroll
        for (int nt = 0; nt < NT; ++nt) {
            long col = n0 + wn + nt * 16 + ln;
#pragma unroll
            for (int r = 0; r < 4; ++r) {
                long row = m0 + wm + mt * 16 + (q << 2) + r;
                float v = acc[mt][nt][r] * scale;
                if (BIAS_MODE == 1) v += bias[row];
                if (BIAS_MODE == 2) v += bias[col];
                long off = row * (long)ldc + col;
                if (OUT_MODE == 0) {
                    ((unsigned char*)C)[off] = to_fp8(v);
                } else {
                    ((_Float16*)C)[off] = (_Float16)v;
                }
            }
        }
    }
}

// --- Merged q|k + v MX GEMM. Grid (8,32,4): z<2 -> qk batch z; z>=2 -> v. ---
__global__ __launch_bounds__(256) void qkv_kernel(
    const unsigned char* __restrict__ hn8, const unsigned char* __restrict__ wqk8,
    const unsigned char* __restrict__ wv8, const float* __restrict__ bqk,
    const float* __restrict__ bv, unsigned char* __restrict__ qk8,
    unsigned char* __restrict__ v8) {
    __shared__ __align__(16) unsigned char As[128 * 128];
    __shared__ __align__(16) unsigned char Bs[128 * 128];
    int z = blockIdx.z;
    if (z < 2) {
        // qk8[b][i][d] = fp8( sum_c hn8[i][c]*wqk8[d][c] + bqk[d] )
        long b = z;
        long m0 = (long)blockIdx.y * 128, n0 = (long)blockIdx.x * 128;
        mx_gemm_body<128, 0, 2>(hn8 + b * 4096 * 512 + m0 * 512, 512,
                                wqk8 + n0 * 512, 512,
                                qk8 + b * 4096 * 1024, 1024,
                                bqk, 512, 1.f, m0, n0, As, Bs);
    } else {
        // v8[b][d][n] = fp8( sum_c wv8[d][c]*hn8[n][c] + bv[d] )
        long b = z - 2;
        int flat = blockIdx.y * 8 + blockIdx.x;  // 0..255
        long m0 = (long)(flat >> 6) * 128, n0 = (long)(flat & 63) * 64;
        mx_gemm_body<64, 0, 1>(wv8 + m0 * 512, 512,
                               hn8 + b * 4096 * 512 + n0 * 512, 512,
                               v8 + b * 512 * 4096, 4096,
                               bv, 512, 1.f, m0, n0, As, Bs);
    }
}

// --- S GEMM: S8[b][i][j] = fp8( scale * sum_c q8[i][c]*k8[j][c] ). ---------
__global__ __launch_bounds__(256) void mx_s_kernel(const unsigned char* __restrict__ QK,
                                                   unsigned char* __restrict__ S,
                                                   float scale) {
    __shared__ __align__(16) unsigned char As[128 * 128];
    __shared__ __align__(16) unsigned char Bs[128 * 128];
    long b = blockIdx.z;
    long m0 = (long)blockIdx.y * 128, n0 = (long)blockIdx.x * 128;
    mx_gemm_body<128, 0, 0>(QK + b * 4096 * 1024 + m0 * 1024, 1024,
                            QK + b * 4096 * 1024 + n0 * 1024 + 512, 1024,
                            S + b * 4096 * 4096, 4096,
                            nullptr, 512, scale, m0, n0, As, Bs);
}

// ---- Row softmax in place: fp8 logits -> fp8 e4m3 probs x64 (same bytes) ---
// Row = 4096 fp8 bytes; thread t owns bytes [16t, 16t+16) — one int4 in/out.
// cvt_f32_fp8's byte index must be a literal constant -> macro unroll.
#define CVT4(dst, base, word)                                   \
    dst[base + 0] = __builtin_amdgcn_cvt_f32_fp8(word, 0);      \
    dst[base + 1] = __builtin_amdgcn_cvt_f32_fp8(word, 1);      \
    dst[base + 2] = __builtin_amdgcn_cvt_f32_fp8(word, 2);      \
    dst[base + 3] = __builtin_amdgcn_cvt_f32_fp8(word, 3);

__global__ __launch_bounds__(256) void softmax_kernel(unsigned char* __restrict__ S) {
    long row = blockIdx.x;
    unsigned char* srow = S + (row << 12);  // row stride 4096 B
    int tid = threadIdx.x;
    int4 d = ((const int4*)srow)[tid];
    float v[16];
    CVT4(v, 0, d.x)
    CVT4(v, 4, d.y)
    CVT4(v, 8, d.z)
    CVT4(v, 12, d.w)
    float mx = -1e30f;
#pragma unroll
    for (int p = 0; p < 16; ++p) mx = fmaxf(mx, v[p]);
    for (int off = 32; off >= 1; off >>= 1) mx = fmaxf(mx, __shfl_xor(mx, off));
    __shared__ float red[4], red2[4];
    int wave = tid >> 6, lane = tid & 63;
    if (lane == 0) red[wave] = mx;
    __syncthreads();
    mx = fmaxf(fmaxf(red[0], red[1]), fmaxf(red[2], red[3]));
    float s = 0.f;
#pragma unroll
    for (int p = 0; p < 16; ++p) {
        v[p] = __expf(v[p] - mx);
        s += v[p];
    }
    for (int off = 32; off >= 1; off >>= 1) s += __shfl_xor(s, off);
    if (lane == 0) red2[wave] = s;
    __syncthreads();
    s = red2[0] + red2[1] + red2[2] + red2[3];
    float inv64 = 64.f / s;  // store P*64; PV epilogue scales by 1/64
    int w[4];
#pragma unroll
    for (int i = 0; i < 4; ++i) {
        w[i] = __builtin_amdgcn_cvt_pk_fp8_f32(v[4 * i] * inv64, v[4 * i + 1] * inv64, 0, false);
        w[i] = __builtin_amdgcn_cvt_pk_fp8_f32(v[4 * i + 2] * inv64, v[4 * i + 3] * inv64, w[i], true);
    }
    ((int4*)srow)[tid] = make_int4(w[0], w[1], w[2], w[3]);
}

// ---------------------------------------------------------------------------
// MX fp8 PV GEMM, BK=256: O[i][c] = (1/64) sum_j P8[i][j]*V8[c][j].
// P8: [b][4096][4096] fp8 (contiguous). V8: [2][512][4096] fp8.
// BM=128, BN=64, BK=256 -> 16 iters, 16 MFMAs/window, LDS 48 KB.
// Grid (64 = m|b, 8 = n) = 512 blocks (2/CU); same-P blocks at flat stride
// 64 == 0 mod 8 -> same XCD, P panel L2-resident.
// ---------------------------------------------------------------------------
__global__ __launch_bounds__(256) void mx_pv_kernel(const unsigned char* __restrict__ P,
                                                    const unsigned char* __restrict__ V,
                                                    __bf16* __restrict__ O) {
    __shared__ __align__(16) unsigned char As[128 * 256];  // 32 KB
    __shared__ __align__(16) unsigned char Bs[64 * 256];   // 16 KB
    const int tid = threadIdx.x;
    const int lane = tid & 63, wave = tid >> 6;
    const int ln = lane & 15, q = lane >> 4;
    const int wm = (wave >> 1) << 6, wn = (wave & 1) << 5;  // 2x2 waves of 64x32
    const int b = blockIdx.x >> 5;
    const long m0 = (long)(blockIdx.x & 31) * 128;
    const long n0 = (long)blockIdx.y * 64;
    const unsigned char* Pb = P + ((long)b * 4096 + m0) * 4096;
    const unsigned char* Vb = V + ((long)b * 512 + n0) * 4096;

    f32x4 acc[4][2] = {};

    for (int k0 = 0; k0 < 4096; k0 += 256) {
        __syncthreads();
#pragma unroll
        for (int p = 0; p < 8; ++p) {
            int c = (p << 8) + tid;  // A: 2048 chunks of 16B (128 rows x 256 B)
            int row = c >> 4, sg = (c & 15) << 4;
            async_copy16(Pb + (long)row * 4096 + k0 + sg, &As[c << 4]);
        }
#pragma unroll
        for (int p = 0; p < 4; ++p) {
            int c = (p << 8) + tid;  // B: 1024 chunks (64 rows x 256 B)
            int row = c >> 4, sg = (c & 15) << 4;
            async_copy16(Vb + (long)row * 4096 + k0 + sg, &Bs[c << 4]);
        }
        __syncthreads();
#pragma unroll
        for (int kk = 0; kk < 2; ++kk) {
            i32x8 af[4], bf[2];
#pragma unroll
            for (int t = 0; t < 4; ++t) {
                const unsigned char* ap =
                    &As[(wm + t * 16 + ln) * 256 + (kk << 7) + (q << 5)];
                *(int4*)&af[t] = *(const int4*)ap;
                *((int4*)&af[t] + 1) = *(const int4*)(ap + 16);
            }
#pragma unroll
            for (int t = 0; t < 2; ++t) {
                const unsigned char* bp =
                    &Bs[(wn + t * 16 + ln) * 256 + (kk << 7) + (q << 5)];
                *(int4*)&bf[t] = *(const int4*)bp;
                *((int4*)&bf[t] + 1) = *(const int4*)(bp + 16);
            }
#pragma unroll
            for (int mt = 0; mt < 4; ++mt)
#pragma unroll
                for (int nt = 0; nt < 2; ++nt)
                    acc[mt][nt] = __builtin_amdgcn_mfma_scale_f32_16x16x128_f8f6f4(
                        af[mt], bf[nt], acc[mt][nt], 0, 0, 0, MXSCALE, 0, MXSCALE);
        }
    }

    __bf16* Ob = O + (long)b * 4096 * 512;
#pragma unroll
    for (int mt = 0; mt < 4; ++mt) {
#pragma unroll
        for (int nt = 0; nt < 2; ++nt) {
            long col = n0 + wn + nt * 16 + ln;
#pragma unroll
            for (int r = 0; r < 4; ++r) {
                long row = m0 + wm + mt * 16 + (q << 2) + r;
                Ob[row * 512 + col] = (__bf16)(acc[mt][nt][r] * 0.015625f);
            }
        }
    }
}

// ---------------------------------------------------------------------------
// Proj GEMM (bf16 m97 structure, precision anchor): out = wp.o_t + bp + x.
// BM=128, BN=64, BK=64. A=wp_b [512][512] bf16, Bt=o_t [n][c] bf16.
// ---------------------------------------------------------------------------
__global__ __launch_bounds__(256) void proj_kernel(
    const __bf16* __restrict__ A, const __bf16* __restrict__ Bt, long bsB,
    float* __restrict__ C, long bsC, const float* __restrict__ bias,
    const float* __restrict__ resid) {
    __shared__ __align__(16) __bf16 As[128][64];
    __shared__ __align__(16) __bf16 Bs[64][64];
    const int tid = threadIdx.x;
    const int wave = tid >> 6, lane = tid & 63;
    const int q = lane >> 4, ln = lane & 15;
    const int wm = wave << 5;  // 4 waves stacked on M, tile 32x64
    const long m0 = (long)blockIdx.y * 128, n0 = (long)blockIdx.x * 64;
    const int b = blockIdx.z;
    const __bf16* Ab = A + m0 * 512;
    const __bf16* Bb = Bt + (long)b * bsB + n0 * 512;

    f32x4 acc[2][4] = {};

    for (int k0 = 0; k0 < 512; k0 += 64) {
        __syncthreads();
#pragma unroll
        for (int p = 0; p < 4; ++p) {
            int c = (p << 8) + tid;
            int row = c >> 3, sg = (c & 7) << 3;
            async_copy16(Ab + (long)row * 512 + k0 + sg, &As[0][0] + (c << 3));
        }
#pragma unroll
        for (int p = 0; p < 2; ++p) {
            int c = (p << 8) + tid;
            int row = c >> 3, sg = (c & 7) << 3;
            async_copy16(Bb + (long)row * 512 + k0 + sg, &Bs[0][0] + (c << 3));
        }
        __syncthreads();
#pragma unroll
        for (int kk = 0; kk < 2; ++kk) {
            bf16x8 af[2], bfr[4];
#pragma unroll
            for (int mt = 0; mt < 2; ++mt)
                af[mt] = *(const bf16x8*)(&As[wm + mt * 16 + ln][(kk << 5) + (q << 3)]);
#pragma unroll
            for (int nt = 0; nt < 4; ++nt)
                bfr[nt] = *(const bf16x8*)(&Bs[nt * 16 + ln][(kk << 5) + (q << 3)]);
#pragma unroll
            for (int mt = 0; mt < 2; ++mt)
#pragma unroll
                for (int nt = 0; nt < 4; ++nt)
                    acc[mt][nt] = __builtin_amdgcn_mfma_f32_16x16x32_bf16(
                        af[mt], bfr[nt], acc[mt][nt], 0, 0, 0);
        }
    }

#pragma unroll
    for (int mt = 0; mt < 2; ++mt) {
#pragma unroll
        for (int nt = 0; nt < 4; ++nt) {
            long col = n0 + nt * 16 + ln;
#pragma unroll
            for (int r = 0; r < 4; ++r) {
                long row = m0 + wm + mt * 16 + (q << 2) + r;
                long off = (long)b * bsC + row * 4096 + col;
                C[off] = acc[mt][nt][r] + bias[row] + resid[off];
            }
        }
    }
}

// ---------------------------------------------------------------------------
extern "C" void kernel_launch(void* const* d_in, const int* in_sizes, int n_in,
                              void* d_out, int out_size, void* d_ws, size_t ws_size,
                              hipStream_t stream) {
    const float* x = (const float*)d_in[0];
    const float* gn_scale = (const float*)d_in[1];
    const float* gn_bias = (const float*)d_in[2];
    const float* wq = (const float*)d_in[3];
    const float* bq = (const float*)d_in[4];
    const float* wk = (const float*)d_in[5];
    const float* bk = (const float*)d_in[6];
    const float* wv = (const float*)d_in[7];
    const float* bv = (const float*)d_in[8];
    const float* wp = (const float*)d_in[9];
    const float* bp = (const float*)d_in[10];
    float* out = (float*)d_out;

    char* ws = (char*)d_ws;
    unsigned char* wqk8 = (unsigned char*)(ws + 0x0);      // [1024][512] fp8
    unsigned char* wv8 = (unsigned char*)(ws + 0x80000);   // [512][512] fp8
    __bf16* wp_b = (__bf16*)(ws + 0xC0000);                // [512][512] bf16
    float* bqk = (float*)(ws + 0x140000);                  // [1024] f32
    float* psum = (float*)(ws + 0x142000);                 // [2][1024] f32
    unsigned char* hn8 = (unsigned char*)(ws + 0x150000);  // [2][4096][512] fp8, 4 MB
    unsigned char* qk8 = (unsigned char*)(ws + 0x550000);  // [2][4096][1024] fp8, 8 MB
    unsigned char* v8 = (unsigned char*)(ws + 0xD50000);   // [2][512][4096] fp8, 4 MB
    __bf16* o_t = (__bf16*)(ws + 0x1150000);               // [2][4096][512] bf16, 8 MB
    unsigned char* S8 = (unsigned char*)(ws + 0x1950000);  // [2][4096][4096] fp8, 32 MB
    (void)ws_size;  // ~58 MB footprint

    // GN channel partials + weight cast, one dispatch
    prep_kernel<<<2048, 256, 0, stream>>>(x, psum, wq, wk, wv, wp, bq, bk,
                                          wqk8, wv8, wp_b, bqk);
    gn_apply_kernel<<<dim3(128, 16, 2), 256, 0, stream>>>(x, gn_scale, gn_bias,
                                                          psum, hn8);

    // q|k and v in one dispatch (1024 blocks)
    qkv_kernel<<<dim3(8, 32, 4), 256, 0, stream>>>(hn8, wqk8, wv8, bqk, bv,
                                                   qk8, v8);

    const float attn_scale = 0.044194173824159216f;  // 512^-0.5
    // S8[b][i][j] (fp8 logits): MX fp8, 2048 blocks, 4 K-iters
    mx_s_kernel<<<dim3(32, 32, 2), 256, 0, stream>>>(qk8, S8, attn_scale);
    // softmax rows in place: fp8 logits -> fp8 probs x64
    softmax_kernel<<<8192, 256, 0, stream>>>(S8);
    // O_t[b][i][c] = (1/64) sum_j P8[i][j]*v8[c][j]  (512 blocks, XCD-paired)
    mx_pv_kernel<<<dim3(64, 8), 256, 0, stream>>>(S8, v8, o_t);

    // proj + residual (bf16 anchor): out[d][n] = wp.o_t + bp[d] + x[d][n]
    proj_kernel<<<dim3(64, 4, 2), 256, 0, stream>>>(
        wp_b, o_t, 4096l * 512, out, 512l * 4096, bp, x);
}

// Round 11
// 188.015 us; speedup vs baseline: 1.1415x; 1.1415x over previous
//
#include <hip/hip_runtime.h>

typedef __bf16 bf16x8 __attribute__((ext_vector_type(8)));
typedef float f32x4 __attribute__((ext_vector_type(4)));
typedef int i32x8 __attribute__((ext_vector_type(8)));

// ---------------------------------------------------------------------------
// Problem constants: B=2, C=512, H=W=64 -> N=4096, 32 groups (16 ch/group)
// ---------------------------------------------------------------------------

#if defined(__has_builtin)
#if __has_builtin(__builtin_amdgcn_global_load_lds)
#define HAS_GLL 1
#endif
#endif

__device__ __forceinline__ void async_copy16(const void* g, void* l) {
#ifdef HAS_GLL
    __builtin_amdgcn_global_load_lds(
        (const __attribute__((address_space(1))) unsigned int*)g,
        (__attribute__((address_space(3))) unsigned int*)l, 16, 0, 0);
#else
    *(int4*)l = *(const int4*)g;
#endif
}

__device__ __forceinline__ unsigned char to_fp8(float v) {
    return (unsigned char)(__builtin_amdgcn_cvt_pk_fp8_f32(v, v, 0, false) & 0xFF);
}

#define MXSCALE 0x7F7F7F7F  // e8m0 1.0 in every byte

// --- Merged: GroupNorm channel partial sums (blocks 0..1023) +
//             weight cast fp32->fp8/bf16 (blocks 1024..2047) ----------------
__global__ __launch_bounds__(256) void prep_kernel(
    const float* __restrict__ x, float* __restrict__ ps,
    const float* __restrict__ wq, const float* __restrict__ wk,
    const float* __restrict__ wv, const float* __restrict__ wp,
    const float* __restrict__ bq, const float* __restrict__ bk,
    unsigned char* __restrict__ wqk8, unsigned char* __restrict__ wv8,
    __bf16* __restrict__ wp_b, float* __restrict__ bqk) {
    if (blockIdx.x >= 1024) {
        int idx = (blockIdx.x - 1024) * 256 + threadIdx.x;  // 262144 = 512*512
        wqk8[idx] = to_fp8(wq[idx]);
        wqk8[262144 + idx] = to_fp8(wk[idx]);
        wv8[idx] = to_fp8(wv[idx]);
        wp_b[idx] = (__bf16)wp[idx];
        if (idx < 512) {
            bqk[idx] = bq[idx];
            bqk[512 + idx] = bk[idx];
        }
        return;
    }
    int blk = blockIdx.x;  // one (b,c) channel: 4096 floats
    const float4* base = (const float4*)x + (size_t)blk * 1024;
    float s1 = 0.f, s2 = 0.f;
#pragma unroll
    for (int i = 0; i < 4; ++i) {
        float4 v = base[threadIdx.x + (i << 8)];
        s1 += v.x + v.y + v.z + v.w;
        s2 += v.x * v.x + v.y * v.y + v.z * v.z + v.w * v.w;
    }
    for (int off = 32; off >= 1; off >>= 1) {
        s1 += __shfl_xor(s1, off);
        s2 += __shfl_xor(s2, off);
    }
    __shared__ float r1[4], r2[4];
    int wave = threadIdx.x >> 6, lane = threadIdx.x & 63;
    if (lane == 0) { r1[wave] = s1; r2[wave] = s2; }
    __syncthreads();
    if (threadIdx.x == 0) {
        ps[blk] = r1[0] + r1[1] + r1[2] + r1[3];
        ps[1024 + blk] = r2[0] + r2[1] + r2[2] + r2[3];
    }
}

// -- GroupNorm finalize + apply + transpose: x[b][c][n] -> hn8[b][n][c] fp8 --
__global__ __launch_bounds__(256) void gn_apply_kernel(const float* __restrict__ x,
                                                       const float* __restrict__ gn_scale,
                                                       const float* __restrict__ gn_bias,
                                                       const float* __restrict__ ps,
                                                       unsigned char* __restrict__ hn8) {
    __shared__ float tile[32][33];
    int b = blockIdx.z;
    int n0 = blockIdx.x * 32, c0 = blockIdx.y * 32;
    int tx = threadIdx.x & 31, ty = threadIdx.x >> 5;  // ty in 0..7
    const float* xb = x + (size_t)b * 512 * 4096;
#pragma unroll
    for (int r = 0; r < 4; ++r) {
        int c = ty + r * 8;
        tile[c][tx] = xb[(size_t)(c0 + c) * 4096 + n0 + tx];
    }
    int c = c0 + tx;
    int g = (b << 5) + (c >> 4);
    float s1 = 0.f, s2 = 0.f;
#pragma unroll
    for (int i = 0; i < 16; ++i) {
        s1 += ps[(g << 4) + i];
        s2 += ps[1024 + (g << 4) + i];
    }
    float m = s1 * (1.f / 65536.f);
    float var = s2 * (1.f / 65536.f) - m * m;
    float rs = rsqrtf(var + 1e-6f);
    float sc = gn_scale[c] * rs;
    float bi = gn_bias[c] - m * sc;
    __syncthreads();
    unsigned char* outp = hn8 + (size_t)b * 4096 * 512;
#pragma unroll
    for (int r = 0; r < 4; ++r) {
        int n = ty + r * 8;
        float v = tile[tx][n];
        outp[(size_t)(n0 + n) * 512 + c] = to_fp8(v * sc + bi);
    }
}

// ---------------------------------------------------------------------------
// Shared MX fp8 GEMM body (m148 structure + XOR-swizzled LDS):
// C = s * A[m][k] * Bt[n][k] (+bias). mfma_scale_f32_16x16x128_f8f6f4,
// BM=128, BK=128. Staging DMAs global segment (s ^ (row&7)) into LDS slot s,
// so fragment reads hit all 32 banks at 2 lanes/bank (free; was 16-way).
// A/B frag: row=lane&15, k=(lane>>4)*32+j. C/D: col=lane&15, row=(lane>>4)*4+r.
// OUT: 0=fp8, 1=fp16. BIAS: 0=none, 1=row (M), 2=col (N).
// ---------------------------------------------------------------------------
template <int BN, int OUT_MODE, int BIAS_MODE>
__device__ __forceinline__ void mx_gemm_body(
    const unsigned char* __restrict__ Ab, int lda,
    const unsigned char* __restrict__ Bb, int ldb,
    void* __restrict__ C, int ldc,
    const float* __restrict__ bias, int K, float scale,
    long m0, long n0, unsigned char* As, unsigned char* Bs) {
    constexpr int NT = BN / 32;  // 4 or 2
    const int tid = threadIdx.x;
    const int lane = tid & 63, wave = tid >> 6;
    const int ln = lane & 15, q = lane >> 4;
    const int wm = (wave >> 1) << 6;
    const int wn = (wave & 1) * (BN / 2);

    f32x4 acc[4][NT] = {};

    for (int k0 = 0; k0 < K; k0 += 128) {
        __syncthreads();
#pragma unroll
        for (int p = 0; p < 4; ++p) {
            int c = (p << 8) + tid;  // A: 1024 chunks of 16B
            int row = c >> 3, sg = ((c & 7) ^ (row & 7)) << 4;  // swizzled src
            async_copy16(Ab + (long)row * lda + k0 + sg, &As[c << 4]);
        }
#pragma unroll
        for (int p = 0; p < BN / 32; ++p) {
            int c = (p << 8) + tid;
            int row = c >> 3, sg = ((c & 7) ^ (row & 7)) << 4;
            async_copy16(Bb + (long)row * ldb + k0 + sg, &Bs[c << 4]);
        }
        __syncthreads();
        i32x8 af[4], bf[NT];
#pragma unroll
        for (int t = 0; t < 4; ++t) {
            int row = wm + t * 16 + ln, e = row & 7;
            const unsigned char* bp = &As[row << 7];
            *(int4*)&af[t] = *(const int4*)(bp + ((((q << 1)) ^ e) << 4));
            *((int4*)&af[t] + 1) = *(const int4*)(bp + ((((q << 1) | 1) ^ e) << 4));
        }
#pragma unroll
        for (int t = 0; t < NT; ++t) {
            int row = wn + t * 16 + ln, e = row & 7;
            const unsigned char* bp = &Bs[row << 7];
            *(int4*)&bf[t] = *(const int4*)(bp + ((((q << 1)) ^ e) << 4));
            *((int4*)&bf[t] + 1) = *(const int4*)(bp + ((((q << 1) | 1) ^ e) << 4));
        }
#pragma unroll
        for (int mt = 0; mt < 4; ++mt)
#pragma unroll
            for (int nt = 0; nt < NT; ++nt)
                acc[mt][nt] = __builtin_amdgcn_mfma_scale_f32_16x16x128_f8f6f4(
                    af[mt], bf[nt], acc[mt][nt], 0, 0, 0, MXSCALE, 0, MXSCALE);
    }

#pragma unroll
    for (int mt = 0; mt < 4; ++mt) {
#pragma unroll
        for (int nt = 0; nt < NT; ++nt) {
            long col = n0 + wn + nt * 16 + ln;
#pragma unroll
            for (int r = 0; r < 4; ++r) {
                long row = m0 + wm + mt * 16 + (q << 2) + r;
                float v = acc[mt][nt][r] * scale;
                if (BIAS_MODE == 1) v += bias[row];
                if (BIAS_MODE == 2) v += bias[col];
                long off = row * (long)ldc + col;
                if (OUT_MODE == 0) {
                    ((unsigned char*)C)[off] = to_fp8(v);
                } else {
                    ((_Float16*)C)[off] = (_Float16)v;
                }
            }
        }
    }
}

// --- Merged q|k + v MX GEMM. Grid (8,32,4): z<2 -> qk batch z; z>=2 -> v. ---
__global__ __launch_bounds__(256) void qkv_kernel(
    const unsigned char* __restrict__ hn8, const unsigned char* __restrict__ wqk8,
    const unsigned char* __restrict__ wv8, const float* __restrict__ bqk,
    const float* __restrict__ bv, unsigned char* __restrict__ qk8,
    unsigned char* __restrict__ v8) {
    __shared__ __align__(16) unsigned char As[128 * 128];
    __shared__ __align__(16) unsigned char Bs[128 * 128];
    int z = blockIdx.z;
    if (z < 2) {
        // qk8[b][i][d] = fp8( sum_c hn8[i][c]*wqk8[d][c] + bqk[d] )
        long b = z;
        long m0 = (long)blockIdx.y * 128, n0 = (long)blockIdx.x * 128;
        mx_gemm_body<128, 0, 2>(hn8 + b * 4096 * 512 + m0 * 512, 512,
                                wqk8 + n0 * 512, 512,
                                qk8 + b * 4096 * 1024, 1024,
                                bqk, 512, 1.f, m0, n0, As, Bs);
    } else {
        // v8[b][d][n] = fp8( sum_c wv8[d][c]*hn8[n][c] + bv[d] )
        long b = z - 2;
        int flat = blockIdx.y * 8 + blockIdx.x;  // 0..255
        long m0 = (long)(flat >> 6) * 128, n0 = (long)(flat & 63) * 64;
        mx_gemm_body<64, 0, 1>(wv8 + m0 * 512, 512,
                               hn8 + b * 4096 * 512 + n0 * 512, 512,
                               v8 + b * 512 * 4096, 4096,
                               bv, 512, 1.f, m0, n0, As, Bs);
    }
}

// --- S GEMM: S8[b][i][j] = fp8( scale * sum_c q8[i][c]*k8[j][c] ). ---------
__global__ __launch_bounds__(256) void mx_s_kernel(const unsigned char* __restrict__ QK,
                                                   unsigned char* __restrict__ S,
                                                   float scale) {
    __shared__ __align__(16) unsigned char As[128 * 128];
    __shared__ __align__(16) unsigned char Bs[128 * 128];
    long b = blockIdx.z;
    long m0 = (long)blockIdx.y * 128, n0 = (long)blockIdx.x * 128;
    mx_gemm_body<128, 0, 0>(QK + b * 4096 * 1024 + m0 * 1024, 1024,
                            QK + b * 4096 * 1024 + n0 * 1024 + 512, 1024,
                            S + b * 4096 * 4096, 4096,
                            nullptr, 512, scale, m0, n0, As, Bs);
}

// ---- Row softmax in place: fp8 logits -> fp8 e4m3 probs x64 (same bytes) ---
// Row = 4096 fp8 bytes; thread t owns bytes [16t, 16t+16) — one int4 in/out.
#define CVT4(dst, base, word)                                   \
    dst[base + 0] = __builtin_amdgcn_cvt_f32_fp8(word, 0);      \
    dst[base + 1] = __builtin_amdgcn_cvt_f32_fp8(word, 1);      \
    dst[base + 2] = __builtin_amdgcn_cvt_f32_fp8(word, 2);      \
    dst[base + 3] = __builtin_amdgcn_cvt_f32_fp8(word, 3);

__global__ __launch_bounds__(256) void softmax_kernel(unsigned char* __restrict__ S) {
    long row = blockIdx.x;
    unsigned char* srow = S + (row << 12);  // row stride 4096 B
    int tid = threadIdx.x;
    int4 d = ((const int4*)srow)[tid];
    float v[16];
    CVT4(v, 0, d.x)
    CVT4(v, 4, d.y)
    CVT4(v, 8, d.z)
    CVT4(v, 12, d.w)
    float mx = -1e30f;
#pragma unroll
    for (int p = 0; p < 16; ++p) mx = fmaxf(mx, v[p]);
    for (int off = 32; off >= 1; off >>= 1) mx = fmaxf(mx, __shfl_xor(mx, off));
    __shared__ float red[4], red2[4];
    int wave = tid >> 6, lane = tid & 63;
    if (lane == 0) red[wave] = mx;
    __syncthreads();
    mx = fmaxf(fmaxf(red[0], red[1]), fmaxf(red[2], red[3]));
    float s = 0.f;
#pragma unroll
    for (int p = 0; p < 16; ++p) {
        v[p] = __expf(v[p] - mx);
        s += v[p];
    }
    for (int off = 32; off >= 1; off >>= 1) s += __shfl_xor(s, off);
    if (lane == 0) red2[wave] = s;
    __syncthreads();
    s = red2[0] + red2[1] + red2[2] + red2[3];
    float inv64 = 64.f / s;  // store P*64; PV epilogue scales by 1/64
    int w[4];
#pragma unroll
    for (int i = 0; i < 4; ++i) {
        w[i] = __builtin_amdgcn_cvt_pk_fp8_f32(v[4 * i] * inv64, v[4 * i + 1] * inv64, 0, false);
        w[i] = __builtin_amdgcn_cvt_pk_fp8_f32(v[4 * i + 2] * inv64, v[4 * i + 3] * inv64, w[i], true);
    }
    ((int4*)srow)[tid] = make_int4(w[0], w[1], w[2], w[3]);
}

// ---------------------------------------------------------------------------
// MX fp8 PV GEMM, BK=128 (r8 geometry) + XOR-swizzled LDS:
// O[i][c] = (1/64) sum_j P8[i][j]*V8[c][j]. P8: [b][4096][4096] fp8.
// V8: [2][512][4096] fp8. BM=128, BN=64 -> 32 iters, 8 MFMAs/window, 24 KB.
// Grid (64 = m|b, 8 = n) = 512 blocks (2/CU); same-P blocks at flat stride
// 64 == 0 mod 8 -> same XCD, P panel L2-resident.
// ---------------------------------------------------------------------------
__global__ __launch_bounds__(256) void mx_pv_kernel(const unsigned char* __restrict__ P,
                                                    const unsigned char* __restrict__ V,
                                                    __bf16* __restrict__ O) {
    __shared__ __align__(16) unsigned char As[128 * 128];  // 16 KB
    __shared__ __align__(16) unsigned char Bs[64 * 128];   // 8 KB
    const int tid = threadIdx.x;
    const int lane = tid & 63, wave = tid >> 6;
    const int ln = lane & 15, q = lane >> 4;
    const int wm = (wave >> 1) << 6, wn = (wave & 1) << 5;  // 2x2 waves of 64x32
    const int b = blockIdx.x >> 5;
    const long m0 = (long)(blockIdx.x & 31) * 128;
    const long n0 = (long)blockIdx.y * 64;
    const unsigned char* Pb = P + ((long)b * 4096 + m0) * 4096;
    const unsigned char* Vb = V + ((long)b * 512 + n0) * 4096;

    f32x4 acc[4][2] = {};

    for (int k0 = 0; k0 < 4096; k0 += 128) {
        __syncthreads();
#pragma unroll
        for (int p = 0; p < 4; ++p) {
            int c = (p << 8) + tid;  // A: 1024 chunks of 16B
            int row = c >> 3, sg = ((c & 7) ^ (row & 7)) << 4;
            async_copy16(Pb + (long)row * 4096 + k0 + sg, &As[c << 4]);
        }
#pragma unroll
        for (int p = 0; p < 2; ++p) {
            int c = (p << 8) + tid;  // B: 512 chunks of 16B
            int row = c >> 3, sg = ((c & 7) ^ (row & 7)) << 4;
            async_copy16(Vb + (long)row * 4096 + k0 + sg, &Bs[c << 4]);
        }
        __syncthreads();
        i32x8 af[4], bf[2];
#pragma unroll
        for (int t = 0; t < 4; ++t) {
            int row = wm + t * 16 + ln, e = row & 7;
            const unsigned char* ap = &As[row << 7];
            *(int4*)&af[t] = *(const int4*)(ap + ((((q << 1)) ^ e) << 4));
            *((int4*)&af[t] + 1) = *(const int4*)(ap + ((((q << 1) | 1) ^ e) << 4));
        }
#pragma unroll
        for (int t = 0; t < 2; ++t) {
            int row = wn + t * 16 + ln, e = row & 7;
            const unsigned char* bp = &Bs[row << 7];
            *(int4*)&bf[t] = *(const int4*)(bp + ((((q << 1)) ^ e) << 4));
            *((int4*)&bf[t] + 1) = *(const int4*)(bp + ((((q << 1) | 1) ^ e) << 4));
        }
#pragma unroll
        for (int mt = 0; mt < 4; ++mt)
#pragma unroll
            for (int nt = 0; nt < 2; ++nt)
                acc[mt][nt] = __builtin_amdgcn_mfma_scale_f32_16x16x128_f8f6f4(
                    af[mt], bf[nt], acc[mt][nt], 0, 0, 0, MXSCALE, 0, MXSCALE);
    }

    __bf16* Ob = O + (long)b * 4096 * 512;
#pragma unroll
    for (int mt = 0; mt < 4; ++mt) {
#pragma unroll
        for (int nt = 0; nt < 2; ++nt) {
            long col = n0 + wn + nt * 16 + ln;
#pragma unroll
            for (int r = 0; r < 4; ++r) {
                long row = m0 + wm + mt * 16 + (q << 2) + r;
                Ob[row * 512 + col] = (__bf16)(acc[mt][nt][r] * 0.015625f);
            }
        }
    }
}

// ---------------------------------------------------------------------------
// Proj GEMM (bf16 m97 structure, precision anchor): out = wp.o_t + bp + x.
// BM=128, BN=64, BK=64. A=wp_b [512][512] bf16, Bt=o_t [n][c] bf16.
// Memory-bound (134 MB fp32 in/out) — left at its roofline.
// ---------------------------------------------------------------------------
__global__ __launch_bounds__(256) void proj_kernel(
    const __bf16* __restrict__ A, const __bf16* __restrict__ Bt, long bsB,
    float* __restrict__ C, long bsC, const float* __restrict__ bias,
    const float* __restrict__ resid) {
    __shared__ __align__(16) __bf16 As[128][64];
    __shared__ __align__(16) __bf16 Bs[64][64];
    const int tid = threadIdx.x;
    const int wave = tid >> 6, lane = tid & 63;
    const int q = lane >> 4, ln = lane & 15;
    const int wm = wave << 5;  // 4 waves stacked on M, tile 32x64
    const long m0 = (long)blockIdx.y * 128, n0 = (long)blockIdx.x * 64;
    const int b = blockIdx.z;
    const __bf16* Ab = A + m0 * 512;
    const __bf16* Bb = Bt + (long)b * bsB + n0 * 512;

    f32x4 acc[2][4] = {};

    for (int k0 = 0; k0 < 512; k0 += 64) {
        __syncthreads();
#pragma unroll
        for (int p = 0; p < 4; ++p) {
            int c = (p << 8) + tid;
            int row = c >> 3, sg = (c & 7) << 3;
            async_copy16(Ab + (long)row * 512 + k0 + sg, &As[0][0] + (c << 3));
        }
#pragma unroll
        for (int p = 0; p < 2; ++p) {
            int c = (p << 8) + tid;
            int row = c >> 3, sg = (c & 7) << 3;
            async_copy16(Bb + (long)row * 512 + k0 + sg, &Bs[0][0] + (c << 3));
        }
        __syncthreads();
#pragma unroll
        for (int kk = 0; kk < 2; ++kk) {
            bf16x8 af[2], bfr[4];
#pragma unroll
            for (int mt = 0; mt < 2; ++mt)
                af[mt] = *(const bf16x8*)(&As[wm + mt * 16 + ln][(kk << 5) + (q << 3)]);
#pragma unroll
            for (int nt = 0; nt < 4; ++nt)
                bfr[nt] = *(const bf16x8*)(&Bs[nt * 16 + ln][(kk << 5) + (q << 3)]);
#pragma unroll
            for (int mt = 0; mt < 2; ++mt)
#pragma unroll
                for (int nt = 0; nt < 4; ++nt)
                    acc[mt][nt] = __builtin_amdgcn_mfma_f32_16x16x32_bf16(
                        af[mt], bfr[nt], acc[mt][nt], 0, 0, 0);
        }
    }

#pragma unroll
    for (int mt = 0; mt < 2; ++mt) {
#pragma unroll
        for (int nt = 0; nt < 4; ++nt) {
            long col = n0 + nt * 16 + ln;
#pragma unroll
            for (int r = 0; r < 4; ++r) {
                long row = m0 + wm + mt * 16 + (q << 2) + r;
                long off = (long)b * bsC + row * 4096 + col;
                C[off] = acc[mt][nt][r] + bias[row] + resid[off];
            }
        }
    }
}

// ---------------------------------------------------------------------------
extern "C" void kernel_launch(void* const* d_in, const int* in_sizes, int n_in,
                              void* d_out, int out_size, void* d_ws, size_t ws_size,
                              hipStream_t stream) {
    const float* x = (const float*)d_in[0];
    const float* gn_scale = (const float*)d_in[1];
    const float* gn_bias = (const float*)d_in[2];
    const float* wq = (const float*)d_in[3];
    const float* bq = (const float*)d_in[4];
    const float* wk = (const float*)d_in[5];
    const float* bk = (const float*)d_in[6];
    const float* wv = (const float*)d_in[7];
    const float* bv = (const float*)d_in[8];
    const float* wp = (const float*)d_in[9];
    const float* bp = (const float*)d_in[10];
    float* out = (float*)d_out;

    char* ws = (char*)d_ws;
    unsigned char* wqk8 = (unsigned char*)(ws + 0x0);      // [1024][512] fp8
    unsigned char* wv8 = (unsigned char*)(ws + 0x80000);   // [512][512] fp8
    __bf16* wp_b = (__bf16*)(ws + 0xC0000);                // [512][512] bf16
    float* bqk = (float*)(ws + 0x140000);                  // [1024] f32
    float* psum = (float*)(ws + 0x142000);                 // [2][1024] f32
    unsigned char* hn8 = (unsigned char*)(ws + 0x150000);  // [2][4096][512] fp8, 4 MB
    unsigned char* qk8 = (unsigned char*)(ws + 0x550000);  // [2][4096][1024] fp8, 8 MB
    unsigned char* v8 = (unsigned char*)(ws + 0xD50000);   // [2][512][4096] fp8, 4 MB
    __bf16* o_t = (__bf16*)(ws + 0x1150000);               // [2][4096][512] bf16, 8 MB
    unsigned char* S8 = (unsigned char*)(ws + 0x1950000);  // [2][4096][4096] fp8, 32 MB
    (void)ws_size;  // ~58 MB footprint

    // GN channel partials + weight cast, one dispatch
    prep_kernel<<<2048, 256, 0, stream>>>(x, psum, wq, wk, wv, wp, bq, bk,
                                          wqk8, wv8, wp_b, bqk);
    gn_apply_kernel<<<dim3(128, 16, 2), 256, 0, stream>>>(x, gn_scale, gn_bias,
                                                          psum, hn8);

    // q|k and v in one dispatch (1024 blocks)
    qkv_kernel<<<dim3(8, 32, 4), 256, 0, stream>>>(hn8, wqk8, wv8, bqk, bv,
                                                   qk8, v8);

    const float attn_scale = 0.044194173824159216f;  // 512^-0.5
    // S8[b][i][j] (fp8 logits): MX fp8, 2048 blocks, 4 K-iters
    mx_s_kernel<<<dim3(32, 32, 2), 256, 0, stream>>>(qk8, S8, attn_scale);
    // softmax rows in place: fp8 logits -> fp8 probs x64
    softmax_kernel<<<8192, 256, 0, stream>>>(S8);
    // O_t[b][i][c] = (1/64) sum_j P8[i][j]*v8[c][j]  (512 blocks, XCD-paired)
    mx_pv_kernel<<<dim3(64, 8), 256, 0, stream>>>(S8, v8, o_t);

    // proj + residual (bf16 anchor): out[d][n] = wp.o_t + bp[d] + x[d][n]
    proj_kernel<<<dim3(64, 4, 2), 256, 0, stream>>>(
        wp_b, o_t, 4096l * 512, out, 512l * 4096, bp, x);
}